// Round 4
// baseline (248.238 us; speedup 1.0000x reference)
//
#include <hip/hip_runtime.h>

// Problem constants (fixed by setup_inputs): B=4096, D=512, H=W=64, N=4096.
#define B_ROWS 4096
#define N_COLS 4096
#define DIM    512
#define LDK    1024   // row stride (elements) of split bf16 arrays [hi(512) | lo(512)]
#define GRID   1024   // 32x32 tile grid; MUST be co-resident (4 blocks/CU)
#define FINAL_BLOCKS 16

typedef __attribute__((ext_vector_type(8))) short short8;
typedef __attribute__((ext_vector_type(4))) float floatx4;

// bf16 round-to-nearest-even split helpers (bit-exact, no API dependence)
__device__ __forceinline__ unsigned short f2bf_rn(float f) {
    unsigned u = __float_as_uint(f);
    u += 0x7fffu + ((u >> 16) & 1u);
    return (unsigned short)(u >> 16);
}
__device__ __forceinline__ float bf2f(unsigned short h) {
    return __uint_as_float(((unsigned)h) << 16);
}

// Monotone float->uint map; (key<<32)|idx gives u64 atomicMin argmin with
// smallest-index tie-break (matches numpy argmin semantics).
__device__ __forceinline__ unsigned long long pack_key(float v, int idx) {
    unsigned u = __float_as_uint(v);
    u = (u & 0x80000000u) ? ~u : (u | 0x80000000u);
    return ((unsigned long long)u << 32) | (unsigned)idx;
}

// Async global->LDS, 16B per lane. LDS dest is wave-uniform base + lane*16.
__device__ __forceinline__ void async16(const unsigned short* g, unsigned short* l) {
    __builtin_amdgcn_global_load_lds(
        (__attribute__((address_space(1))) void*)g,
        (__attribute__((address_space(3))) void*)l, 16, 0, 0);
}

// Fused: convert -> grid barrier -> dist GEMM + argmin -> grid barrier ->
// finalize. Co-residency contract: GRID=1024 at 4 blocks/CU
// (launch_bounds(256,4): <=128 unified regs/thread; LDS 32KB).
__global__ __launch_bounds__(256, 4) void som_fused(
    const float* __restrict__ X, const float* __restrict__ Wt,
    unsigned short* __restrict__ Xc, unsigned short* __restrict__ Wc,
    float* __restrict__ x_sq, float* __restrict__ w_sq,
    unsigned long long* __restrict__ packed,
    unsigned* __restrict__ sync0, unsigned* __restrict__ sync1,
    float* __restrict__ out)
{
    __shared__ unsigned short Ah[128 * 32];   // row-major, 32 elems (64 B)/row
    __shared__ unsigned short Al[128 * 32];
    __shared__ unsigned short Bh[128 * 32];
    __shared__ unsigned short Bl[128 * 32];
    const int tid  = threadIdx.x;
    const int wave = tid >> 6, lane = tid & 63;

    // ---------------- Phase A: split-convert 8 rows per block ----------------
    #pragma unroll
    for (int rr = 0; rr < 2; ++rr) {
        int grow = blockIdx.x * 8 + rr * 4 + wave;      // 0..8191
        bool isX = grow < B_ROWS;
        const float* src = isX ? (X + (size_t)grow * DIM)
                               : (Wt + (size_t)(grow - B_ROWS) * DIM);
        const float4* p4 = (const float4*)src;
        float4 a = p4[lane * 2], b = p4[lane * 2 + 1];
        float f[8] = {a.x, a.y, a.z, a.w, b.x, b.y, b.z, b.w};
        unsigned short hi[8], lo[8];
        float s = 0.f;
        #pragma unroll
        for (int t = 0; t < 8; ++t) {
            hi[t] = f2bf_rn(f[t]);
            lo[t] = f2bf_rn(f[t] - bf2f(hi[t]));
            s = fmaf(f[t], f[t], s);
        }
        unsigned short* dst = (isX ? Xc + (size_t)grow * LDK
                                   : Wc + (size_t)(grow - B_ROWS) * LDK) + lane * 8;
        *(ushort4*)(dst)       = make_ushort4(hi[0], hi[1], hi[2], hi[3]);
        *(ushort4*)(dst + 4)   = make_ushort4(hi[4], hi[5], hi[6], hi[7]);
        *(ushort4*)(dst + 512) = make_ushort4(lo[0], lo[1], lo[2], lo[3]);
        *(ushort4*)(dst + 516) = make_ushort4(lo[4], lo[5], lo[6], lo[7]);
        #pragma unroll
        for (int off = 32; off >= 1; off >>= 1) s += __shfl_xor(s, off, 64);
        if (lane == 0) {
            if (isX) { x_sq[grow] = s; packed[grow] = ~0ull; }
            else     { w_sq[grow - B_ROWS] = s; }
        }
    }

    // ---- Grid barrier 0 (release-add, acquire-spin; coop-groups pattern) ----
    __syncthreads();
    if (tid == 0) {
        __threadfence();
        __hip_atomic_fetch_add(sync0, 1u, __ATOMIC_ACQ_REL, __HIP_MEMORY_SCOPE_AGENT);
        while (__hip_atomic_load(sync0, __ATOMIC_ACQUIRE, __HIP_MEMORY_SCOPE_AGENT) < GRID)
            __builtin_amdgcn_s_sleep(2);
        __threadfence();   // invalidate stale L1/L2 before phase-B reads
    }
    __syncthreads();

    // ---------------- Phase B: merged split-bf16 GEMM + argmin ----------------
    const int bm = blockIdx.x >> 5, bn = blockIdx.x & 31;
    const int wr = wave >> 1, wc = wave & 1;       // 2x2 wave grid
    const int quad = lane >> 4, t16 = lane & 15;

    const int srow = lane >> 2;          // 0..15
    const int scol = (lane & 3) * 8;     // element offset (16 B granules)
    const unsigned short* gAh = Xc + (size_t)(bm * 128 + wave * 32 + srow) * LDK + scol;
    const unsigned short* gBh = Wc + (size_t)(bn * 128 + wave * 32 + srow) * LDK + scol;
    const unsigned short* gAl = gAh + 512;
    const unsigned short* gBl = gBh + 512;
    unsigned short* lAh = &Ah[(wave * 32) * 32];
    unsigned short* lAl = &Al[(wave * 32) * 32];
    unsigned short* lBh = &Bh[(wave * 32) * 32];
    unsigned short* lBl = &Bl[(wave * 32) * 32];

    const unsigned short* pah = &Ah[(wr * 64 + t16) * 32 + quad * 8];
    const unsigned short* pal = &Al[(wr * 64 + t16) * 32 + quad * 8];
    const unsigned short* pbh = &Bh[(wc * 64 + t16) * 32 + quad * 8];
    const unsigned short* pbl = &Bl[(wc * 64 + t16) * 32 + quad * 8];

    floatx4 acc[4][4];
    #pragma unroll
    for (int i = 0; i < 4; ++i)
        #pragma unroll
        for (int j = 0; j < 4; ++j) acc[i][j] = (floatx4){0.f, 0.f, 0.f, 0.f};

    #pragma unroll 1
    for (int k0 = 0; k0 < DIM; k0 += 32) {
        __syncthreads();                       // prev tile fully consumed
        async16(gAh + k0,            lAh);
        async16(gAh + k0 + 16 * LDK, lAh + 16 * 32);
        async16(gAl + k0,            lAl);
        async16(gAl + k0 + 16 * LDK, lAl + 16 * 32);
        async16(gBh + k0,            lBh);
        async16(gBh + k0 + 16 * LDK, lBh + 16 * 32);
        async16(gBl + k0,            lBl);
        async16(gBl + k0 + 16 * LDK, lBl + 16 * 32);
        __syncthreads();                       // staged data visible

        short8 ah[4], bh[4], x[4];
        #pragma unroll
        for (int i = 0; i < 4; ++i) ah[i] = *(const short8*)(pah + i * 16 * 32);
        #pragma unroll
        for (int j = 0; j < 4; ++j) bh[j] = *(const short8*)(pbh + j * 16 * 32);
        #pragma unroll
        for (int i = 0; i < 4; ++i)
            #pragma unroll
            for (int j = 0; j < 4; ++j)
                acc[i][j] = __builtin_amdgcn_mfma_f32_16x16x32_bf16(
                    ah[i], bh[j], acc[i][j], 0, 0, 0);

        #pragma unroll
        for (int j = 0; j < 4; ++j) x[j] = *(const short8*)(pbl + j * 16 * 32);
        #pragma unroll
        for (int i = 0; i < 4; ++i)
            #pragma unroll
            for (int j = 0; j < 4; ++j)
                acc[i][j] = __builtin_amdgcn_mfma_f32_16x16x32_bf16(
                    ah[i], x[j], acc[i][j], 0, 0, 0);

        #pragma unroll
        for (int i = 0; i < 4; ++i) x[i] = *(const short8*)(pal + i * 16 * 32);
        #pragma unroll
        for (int i = 0; i < 4; ++i)
            #pragma unroll
            for (int j = 0; j < 4; ++j)
                acc[i][j] = __builtin_amdgcn_mfma_f32_16x16x32_bf16(
                    x[i], bh[j], acc[i][j], 0, 0, 0);
    }

    // Epilogue: val = w_sq - 2*dot. C/D layout: col=t16, row=quad*4+reg.
    {
        const int col0 = bn * 128 + wc * 64 + t16;
        float wq[4];
        #pragma unroll
        for (int j = 0; j < 4; ++j) wq[j] = w_sq[col0 + j * 16];
        const int row_base = bm * 128 + wr * 64 + quad * 4;
        #pragma unroll
        for (int i = 0; i < 4; ++i) {
            #pragma unroll
            for (int r = 0; r < 4; ++r) {
                unsigned long long best = ~0ull;
                #pragma unroll
                for (int j = 0; j < 4; ++j) {
                    float val = fmaf(-2.f, acc[i][j][r], wq[j]);
                    unsigned long long key = pack_key(val, col0 + j * 16);
                    best = (key < best) ? key : best;
                }
                #pragma unroll
                for (int m = 1; m <= 8; m <<= 1) {
                    unsigned long long o = __shfl_xor(best, m, 64);
                    best = (o < best) ? o : best;
                }
                if (t16 == 0)
                    atomicMin(&packed[row_base + i * 16 + r], best);
            }
        }
    }

    // ---- Grid barrier 1: signal; only finalizer blocks wait ----
    __syncthreads();     // drains each wave's outstanding atomics (vmcnt)
    if (tid == 0) {
        __threadfence();
        __hip_atomic_fetch_add(sync1, 1u, __ATOMIC_ACQ_REL, __HIP_MEMORY_SCOPE_AGENT);
    }
    if (blockIdx.x >= FINAL_BLOCKS) return;

    if (tid == 0) {
        while (__hip_atomic_load(sync1, __ATOMIC_ACQUIRE, __HIP_MEMORY_SCOPE_AGENT) < GRID)
            __builtin_amdgcn_s_sleep(2);
        __threadfence();
    }
    __syncthreads();

    // ---------------- Phase C: finalize 256 rows per block ----------------
    {
        int b = blockIdx.x * 256 + tid;  // 0..4095
        // packed-init lines may be stale in our own L2 -> coherent atomic load
        unsigned long long p = __hip_atomic_load(&packed[b], __ATOMIC_RELAXED,
                                                 __HIP_MEMORY_SCOPE_AGENT);
        unsigned idx = (unsigned)(p & 0xffffffffull);
        unsigned key = (unsigned)(p >> 32);
        unsigned u = (key & 0x80000000u) ? (key & 0x7fffffffu) : ~key;
        float val = __uint_as_float(u);
        float sq = fmaxf(x_sq[b] + val, 0.f);
        out[2 * b]     = (float)(idx >> 6);   // y = idx / 64
        out[2 * b + 1] = (float)(idx & 63);   // x = idx % 64
        out[2 * B_ROWS + b] = sqrtf(sq);
    }
}

extern "C" void kernel_launch(void* const* d_in, const int* in_sizes, int n_in,
                              void* d_out, int out_size, void* d_ws, size_t ws_size,
                              hipStream_t stream) {
    const float* X  = (const float*)d_in[0];   // (4096, 512)
    const float* Wt = (const float*)d_in[1];   // (64, 64, 512) -> (4096, 512)
    float* out = (float*)d_out;

    // ws layout: [0,32K) packed u64[4096]; [32K,48K) x_sq; [48K,64K) w_sq;
    // [64K,64K+256) sync counters; [72K, 72K+8M) Xc; [72K+8M, 72K+16M) Wc.
    unsigned long long* packed = (unsigned long long*)d_ws;
    float* x_sq = (float*)((char*)d_ws + (32 << 10));
    float* w_sq = (float*)((char*)d_ws + (48 << 10));
    unsigned* syncb = (unsigned*)((char*)d_ws + (64 << 10));
    unsigned short* Xc = (unsigned short*)((char*)d_ws + (72 << 10));
    unsigned short* Wc = (unsigned short*)((char*)d_ws + (72 << 10) + ((size_t)B_ROWS * LDK * 2));

    hipMemsetAsync(syncb, 0, 256, stream);   // zero the two barrier counters
    som_fused<<<dim3(GRID), dim3(256), 0, stream>>>(
        X, Wt, Xc, Wc, x_sq, w_sq, packed, syncb, syncb + 1, out);
}

// Round 5
// 217.645 us; speedup vs baseline: 1.1406x; 1.1406x over previous
//
#include <hip/hip_runtime.h>

// Problem constants (fixed by setup_inputs): B=4096, D=512, H=W=64, N=4096.
#define B_ROWS 4096
#define N_COLS 4096
#define DIM    512
#define LDK    1024   // row stride (elements) of split bf16 arrays [hi(512) | lo(512)]
#define GRID   1024   // 32x32 tile grid; MUST be co-resident (4 blocks/CU)

typedef __attribute__((ext_vector_type(8))) short short8;
typedef __attribute__((ext_vector_type(4))) float floatx4;

// bf16 round-to-nearest-even split helpers (bit-exact, no API dependence)
__device__ __forceinline__ unsigned short f2bf_rn(float f) {
    unsigned u = __float_as_uint(f);
    u += 0x7fffu + ((u >> 16) & 1u);
    return (unsigned short)(u >> 16);
}
__device__ __forceinline__ float bf2f(unsigned short h) {
    return __uint_as_float(((unsigned)h) << 16);
}

// Monotone float->uint map; (key<<32)|idx gives u64 atomicMin argmin with
// smallest-index tie-break (matches numpy argmin semantics).
__device__ __forceinline__ unsigned long long pack_key(float v, int idx) {
    unsigned u = __float_as_uint(v);
    u = (u & 0x80000000u) ? ~u : (u | 0x80000000u);
    return ((unsigned long long)u << 32) | (unsigned)idx;
}

// Async global->LDS, 16B per lane. LDS dest is wave-uniform base + lane*16.
__device__ __forceinline__ void async16(const unsigned short* g, unsigned short* l) {
    __builtin_amdgcn_global_load_lds(
        (__attribute__((address_space(1))) void*)g,
        (__attribute__((address_space(3))) void*)l, 16, 0, 0);
}

// Fused convert -> grid barrier -> GEMM+argmin -> per-bm counter -> finalize.
//
// Sync protocol (the R4 version ACQUIRE-polled at agent scope; each poll
// lowers to buffer_inv, nuking that XCD's L2 ~19M times/sec during waits --
// phase B's L2-absorbed staging collapsed and the kernel stretched 3.6x):
//   * signal  = __hip_atomic_fetch_add(RELEASE)  -> buffer_wbl2, NO invalidate
//   * poll    = relaxed atomic load              -> no cache maintenance
//   * acquire = NOT NEEDED: readers never cached producer lines pre-barrier
//     (cross-XCD lines absent -> miss to LLC which holds flushed data;
//      same-XCD lines are clean-correct after the writer's wbl2).
//   * packed/counters are read with agent-scope atomic loads (coherence pt).
__global__ __launch_bounds__(256, 4) void som_fused(
    const float* __restrict__ X, const float* __restrict__ Wt,
    unsigned short* __restrict__ Xc, unsigned short* __restrict__ Wc,
    float* __restrict__ x_sq, float* __restrict__ w_sq,
    unsigned long long* __restrict__ packed,
    unsigned* __restrict__ sync0, unsigned* __restrict__ done,  // done[32]
    float* __restrict__ out)
{
    __shared__ unsigned short Ah[128 * 32];   // row-major, 32 elems (64 B)/row
    __shared__ unsigned short Al[128 * 32];
    __shared__ unsigned short Bh[128 * 32];
    __shared__ unsigned short Bl[128 * 32];
    const int tid  = threadIdx.x;
    const int wave = tid >> 6, lane = tid & 63;

    // ---------------- Phase A: split-convert 8 rows per block ----------------
    #pragma unroll
    for (int rr = 0; rr < 2; ++rr) {
        int grow = blockIdx.x * 8 + rr * 4 + wave;      // 0..8191
        bool isX = grow < B_ROWS;
        const float* src = isX ? (X + (size_t)grow * DIM)
                               : (Wt + (size_t)(grow - B_ROWS) * DIM);
        const float4* p4 = (const float4*)src;
        float4 a = p4[lane * 2], b = p4[lane * 2 + 1];
        float f[8] = {a.x, a.y, a.z, a.w, b.x, b.y, b.z, b.w};
        unsigned short hi[8], lo[8];
        float s = 0.f;
        #pragma unroll
        for (int t = 0; t < 8; ++t) {
            hi[t] = f2bf_rn(f[t]);
            lo[t] = f2bf_rn(f[t] - bf2f(hi[t]));
            s = fmaf(f[t], f[t], s);
        }
        unsigned short* dst = (isX ? Xc + (size_t)grow * LDK
                                   : Wc + (size_t)(grow - B_ROWS) * LDK) + lane * 8;
        *(ushort4*)(dst)       = make_ushort4(hi[0], hi[1], hi[2], hi[3]);
        *(ushort4*)(dst + 4)   = make_ushort4(hi[4], hi[5], hi[6], hi[7]);
        *(ushort4*)(dst + 512) = make_ushort4(lo[0], lo[1], lo[2], lo[3]);
        *(ushort4*)(dst + 516) = make_ushort4(lo[4], lo[5], lo[6], lo[7]);
        #pragma unroll
        for (int off = 32; off >= 1; off >>= 1) s += __shfl_xor(s, off, 64);
        if (lane == 0) {
            if (isX) { x_sq[grow] = s; packed[grow] = ~0ull; }
            else     { w_sq[grow - B_ROWS] = s; }
        }
    }

    // ---- Grid barrier 0: release-add, RELAXED poll (no invalidates) ----
    __syncthreads();
    if (tid == 0) {
        __hip_atomic_fetch_add(sync0, 1u, __ATOMIC_RELEASE, __HIP_MEMORY_SCOPE_AGENT);
        while (__hip_atomic_load(sync0, __ATOMIC_RELAXED, __HIP_MEMORY_SCOPE_AGENT) < GRID)
            __builtin_amdgcn_s_sleep(8);
    }
    __syncthreads();

    // ---------------- Phase B: merged split-bf16 GEMM + argmin ----------------
    const int bm = blockIdx.x >> 5, bn = blockIdx.x & 31;
    const int wr = wave >> 1, wc = wave & 1;       // 2x2 wave grid
    const int quad = lane >> 4, t16 = lane & 15;

    const int srow = lane >> 2;          // 0..15
    const int scol = (lane & 3) * 8;     // element offset (16 B granules)
    const unsigned short* gAh = Xc + (size_t)(bm * 128 + wave * 32 + srow) * LDK + scol;
    const unsigned short* gBh = Wc + (size_t)(bn * 128 + wave * 32 + srow) * LDK + scol;
    const unsigned short* gAl = gAh + 512;
    const unsigned short* gBl = gBh + 512;
    unsigned short* lAh = &Ah[(wave * 32) * 32];
    unsigned short* lAl = &Al[(wave * 32) * 32];
    unsigned short* lBh = &Bh[(wave * 32) * 32];
    unsigned short* lBl = &Bl[(wave * 32) * 32];

    const unsigned short* pah = &Ah[(wr * 64 + t16) * 32 + quad * 8];
    const unsigned short* pal = &Al[(wr * 64 + t16) * 32 + quad * 8];
    const unsigned short* pbh = &Bh[(wc * 64 + t16) * 32 + quad * 8];
    const unsigned short* pbl = &Bl[(wc * 64 + t16) * 32 + quad * 8];

    floatx4 acc[4][4];
    #pragma unroll
    for (int i = 0; i < 4; ++i)
        #pragma unroll
        for (int j = 0; j < 4; ++j) acc[i][j] = (floatx4){0.f, 0.f, 0.f, 0.f};

    // Rotated K start de-convoys the post-barrier lockstep memory bursts.
    const int krot = (blockIdx.x * 5) & 15;
    #pragma unroll 1
    for (int it = 0; it < 16; ++it) {
        const int k0 = ((it + krot) & 15) * 32;
        __syncthreads();                       // prev tile fully consumed
        async16(gAh + k0,            lAh);
        async16(gAh + k0 + 16 * LDK, lAh + 16 * 32);
        async16(gAl + k0,            lAl);
        async16(gAl + k0 + 16 * LDK, lAl + 16 * 32);
        async16(gBh + k0,            lBh);
        async16(gBh + k0 + 16 * LDK, lBh + 16 * 32);
        async16(gBl + k0,            lBl);
        async16(gBl + k0 + 16 * LDK, lBl + 16 * 32);
        __syncthreads();                       // staged data visible

        short8 ah[4], bh[4], x[4];
        #pragma unroll
        for (int i = 0; i < 4; ++i) ah[i] = *(const short8*)(pah + i * 16 * 32);
        #pragma unroll
        for (int j = 0; j < 4; ++j) bh[j] = *(const short8*)(pbh + j * 16 * 32);
        #pragma unroll
        for (int i = 0; i < 4; ++i)
            #pragma unroll
            for (int j = 0; j < 4; ++j)
                acc[i][j] = __builtin_amdgcn_mfma_f32_16x16x32_bf16(
                    ah[i], bh[j], acc[i][j], 0, 0, 0);

        #pragma unroll
        for (int j = 0; j < 4; ++j) x[j] = *(const short8*)(pbl + j * 16 * 32);
        #pragma unroll
        for (int i = 0; i < 4; ++i)
            #pragma unroll
            for (int j = 0; j < 4; ++j)
                acc[i][j] = __builtin_amdgcn_mfma_f32_16x16x32_bf16(
                    ah[i], x[j], acc[i][j], 0, 0, 0);

        #pragma unroll
        for (int i = 0; i < 4; ++i) x[i] = *(const short8*)(pal + i * 16 * 32);
        #pragma unroll
        for (int i = 0; i < 4; ++i)
            #pragma unroll
            for (int j = 0; j < 4; ++j)
                acc[i][j] = __builtin_amdgcn_mfma_f32_16x16x32_bf16(
                    x[i], bh[j], acc[i][j], 0, 0, 0);
    }

    // Epilogue: val = w_sq - 2*dot. C/D layout: col=t16, row=quad*4+reg.
    {
        const int col0 = bn * 128 + wc * 64 + t16;
        float wq[4];
        #pragma unroll
        for (int j = 0; j < 4; ++j) wq[j] = w_sq[col0 + j * 16];
        const int row_base = bm * 128 + wr * 64 + quad * 4;
        #pragma unroll
        for (int i = 0; i < 4; ++i) {
            #pragma unroll
            for (int r = 0; r < 4; ++r) {
                unsigned long long best = ~0ull;
                #pragma unroll
                for (int j = 0; j < 4; ++j) {
                    float val = fmaf(-2.f, acc[i][j][r], wq[j]);
                    unsigned long long key = pack_key(val, col0 + j * 16);
                    best = (key < best) ? key : best;
                }
                #pragma unroll
                for (int m = 1; m <= 8; m <<= 1) {
                    unsigned long long o = __shfl_xor(best, m, 64);
                    best = (o < best) ? o : best;
                }
                if (t16 == 0)
                    atomicMin(&packed[row_base + i * 16 + r], best);
            }
        }
    }

    // ---- Per-bm completion: release-add; only bn==0 blocks poll + finalize ----
    __syncthreads();
    if (tid == 0)
        __hip_atomic_fetch_add(&done[bm], 1u, __ATOMIC_RELEASE, __HIP_MEMORY_SCOPE_AGENT);
    if (bn != 0) return;

    if (tid == 0) {
        while (__hip_atomic_load(&done[bm], __ATOMIC_RELAXED, __HIP_MEMORY_SCOPE_AGENT) < 32)
            __builtin_amdgcn_s_sleep(8);
    }
    __syncthreads();

    // ---------------- Phase C: finalize 128 rows of this bm group ----------------
    if (tid < 128) {
        int b = bm * 128 + tid;
        unsigned long long p = __hip_atomic_load(&packed[b], __ATOMIC_RELAXED,
                                                 __HIP_MEMORY_SCOPE_AGENT);
        unsigned idx = (unsigned)(p & 0xffffffffull);
        unsigned key = (unsigned)(p >> 32);
        unsigned u = (key & 0x80000000u) ? (key & 0x7fffffffu) : ~key;
        float val = __uint_as_float(u);
        float sq = fmaxf(x_sq[b] + val, 0.f);
        out[2 * b]     = (float)(idx >> 6);   // y = idx / 64
        out[2 * b + 1] = (float)(idx & 63);   // x = idx % 64
        out[2 * B_ROWS + b] = sqrtf(sq);
    }
}

extern "C" void kernel_launch(void* const* d_in, const int* in_sizes, int n_in,
                              void* d_out, int out_size, void* d_ws, size_t ws_size,
                              hipStream_t stream) {
    const float* X  = (const float*)d_in[0];   // (4096, 512)
    const float* Wt = (const float*)d_in[1];   // (64, 64, 512) -> (4096, 512)
    float* out = (float*)d_out;

    // ws layout: [0,32K) packed u64[4096]; [32K,48K) x_sq; [48K,64K) w_sq;
    // [64K,+4) sync0; [64K+64, +128) done[32]; [72K,+8M) Xc; [+8M,+16M) Wc.
    unsigned long long* packed = (unsigned long long*)d_ws;
    float* x_sq = (float*)((char*)d_ws + (32 << 10));
    float* w_sq = (float*)((char*)d_ws + (48 << 10));
    unsigned* sync0 = (unsigned*)((char*)d_ws + (64 << 10));
    unsigned* done  = (unsigned*)((char*)d_ws + (64 << 10) + 64);
    unsigned short* Xc = (unsigned short*)((char*)d_ws + (72 << 10));
    unsigned short* Wc = (unsigned short*)((char*)d_ws + (72 << 10) + ((size_t)B_ROWS * LDK * 2));

    hipMemsetAsync(sync0, 0, 256, stream);   // zero barrier + done counters
    som_fused<<<dim3(GRID), dim3(256), 0, stream>>>(
        X, Wt, Xc, Wc, x_sq, w_sq, packed, sync0, done, out);
}

// Round 6
// 198.110 us; speedup vs baseline: 1.2530x; 1.0986x over previous
//
#include <hip/hip_runtime.h>

// Problem constants (fixed by setup_inputs): B=4096, D=512, H=W=64, N=4096.
#define B_ROWS 4096
#define N_COLS 4096
#define DIM    512
#define LDK    1024   // row stride (elements) of split bf16 arrays [hi(512) | lo(512)]
#define GRID   1024   // 32x32 tile grid

typedef __attribute__((ext_vector_type(8))) short short8;
typedef __attribute__((ext_vector_type(4))) float floatx4;

// bf16 round-to-nearest-even split helpers (bit-exact, no API dependence)
__device__ __forceinline__ unsigned short f2bf_rn(float f) {
    unsigned u = __float_as_uint(f);
    u += 0x7fffu + ((u >> 16) & 1u);
    return (unsigned short)(u >> 16);
}
__device__ __forceinline__ float bf2f(unsigned short h) {
    return __uint_as_float(((unsigned)h) << 16);
}

// Monotone float->uint map; (key<<32)|idx gives u64 atomicMin argmin with
// smallest-index tie-break (matches numpy argmin semantics).
__device__ __forceinline__ unsigned long long pack_key(float v, int idx) {
    unsigned u = __float_as_uint(v);
    u = (u & 0x80000000u) ? ~u : (u | 0x80000000u);
    return ((unsigned long long)u << 32) | (unsigned)idx;
}

// Async global->LDS, 16B per lane. LDS dest is wave-uniform base + lane*16.
__device__ __forceinline__ void async16(const unsigned short* g, unsigned short* l) {
    __builtin_amdgcn_global_load_lds(
        (__attribute__((address_space(1))) void*)g,
        (__attribute__((address_space(3))) void*)l, 16, 0, 0);
}

// Fused convert -> slab-ready flags -> GEMM+argmin -> per-bm counter -> finalize.
//
// Sync protocol lessons (R4/R5 post-mortems):
//   * NEVER acquire-poll at agent scope: each poll -> buffer_inv -> nukes the
//     polling XCD's L2 and collapses phase B's L2-absorbed staging (R4, 3.6x).
//   * signal = fetch_add(RELEASE) -> buffer_wbl2 (writeback, NO invalidate);
//     poll = RELAXED atomic load (no cache maintenance). Acquire is unneeded:
//     kernel-boundary implicit invalidate clears prior-launch lines, and a
//     consumer XCD's L2 only ever acquires producer lines as clean copies
//     pulled from LLC after the producer's wbl2 (this is why R5 passed).
//   * NO global K-rotation: lockstep k keeps all blocks on the same ~1MB
//     k-slice -> L2/LLC absorbs the 512MB staging re-read (R5's krot doubled
//     FETCH_SIZE 45->84MB and stretched phase B ~2x).
//   * Fine-grained readiness instead of a grid barrier: block (bm,bn) waits
//     only for Xc slab bm (blocks 16bm..+15) and Wc slab bn (blocks
//     512+16bn..+15). Producers never wait => deadlock-free at ANY occupancy.
__global__ __launch_bounds__(256, 4) void som_fused(
    const float* __restrict__ X, const float* __restrict__ Wt,
    unsigned short* __restrict__ Xc, unsigned short* __restrict__ Wc,
    float* __restrict__ x_sq, float* __restrict__ w_sq,
    unsigned long long* __restrict__ packed,
    unsigned* __restrict__ ready,   // ready[64]: 0..31 Xc slabs, 32..63 Wc slabs
    unsigned* __restrict__ done,    // done[32] per-bm completion
    float* __restrict__ out)
{
    __shared__ unsigned short Ah[128 * 32];   // row-major, 32 elems (64 B)/row
    __shared__ unsigned short Al[128 * 32];
    __shared__ unsigned short Bh[128 * 32];
    __shared__ unsigned short Bl[128 * 32];
    const int tid  = threadIdx.x;
    const int wave = tid >> 6, lane = tid & 63;

    // ---------------- Phase A: split-convert 8 rows per block ----------------
    // Block i covers rows 8i..8i+7 -> exactly one 128-row slab (i/16).
    #pragma unroll
    for (int rr = 0; rr < 2; ++rr) {
        int grow = blockIdx.x * 8 + rr * 4 + wave;      // 0..8191
        bool isX = grow < B_ROWS;
        const float* src = isX ? (X + (size_t)grow * DIM)
                               : (Wt + (size_t)(grow - B_ROWS) * DIM);
        const float4* p4 = (const float4*)src;
        float4 a = p4[lane * 2], b = p4[lane * 2 + 1];
        float f[8] = {a.x, a.y, a.z, a.w, b.x, b.y, b.z, b.w};
        unsigned short hi[8], lo[8];
        float s = 0.f;
        #pragma unroll
        for (int t = 0; t < 8; ++t) {
            hi[t] = f2bf_rn(f[t]);
            lo[t] = f2bf_rn(f[t] - bf2f(hi[t]));
            s = fmaf(f[t], f[t], s);
        }
        unsigned short* dst = (isX ? Xc + (size_t)grow * LDK
                                   : Wc + (size_t)(grow - B_ROWS) * LDK) + lane * 8;
        *(ushort4*)(dst)       = make_ushort4(hi[0], hi[1], hi[2], hi[3]);
        *(ushort4*)(dst + 4)   = make_ushort4(hi[4], hi[5], hi[6], hi[7]);
        *(ushort4*)(dst + 512) = make_ushort4(lo[0], lo[1], lo[2], lo[3]);
        *(ushort4*)(dst + 516) = make_ushort4(lo[4], lo[5], lo[6], lo[7]);
        #pragma unroll
        for (int off = 32; off >= 1; off >>= 1) s += __shfl_xor(s, off, 64);
        if (lane == 0) {
            if (isX) { x_sq[grow] = s; packed[grow] = ~0ull; }
            else     { w_sq[grow - B_ROWS] = s; }
        }
    }

    // ---- Signal slab readiness (release flushes our L2 to LLC first) ----
    __syncthreads();                 // all waves' stores drained (vmcnt 0)
    if (tid == 0)
        __hip_atomic_fetch_add(&ready[blockIdx.x >> 4], 1u,
                               __ATOMIC_RELEASE, __HIP_MEMORY_SCOPE_AGENT);

    // ---- Wait for the two slabs this block consumes (relaxed polls) ----
    const int bm = blockIdx.x >> 5, bn = blockIdx.x & 31;
    if (tid == 0) {
        while (__hip_atomic_load(&ready[bm], __ATOMIC_RELAXED,
                                 __HIP_MEMORY_SCOPE_AGENT) < 16u ||
               __hip_atomic_load(&ready[32 + bn], __ATOMIC_RELAXED,
                                 __HIP_MEMORY_SCOPE_AGENT) < 16u)
            __builtin_amdgcn_s_sleep(1);
    }
    __syncthreads();

    // ---------------- Phase B: merged split-bf16 GEMM + argmin ----------------
    const int wr = wave >> 1, wc = wave & 1;       // 2x2 wave grid
    const int quad = lane >> 4, t16 = lane & 15;

    const int srow = lane >> 2;          // 0..15
    const int scol = (lane & 3) * 8;     // element offset (16 B granules)
    const unsigned short* gAh = Xc + (size_t)(bm * 128 + wave * 32 + srow) * LDK + scol;
    const unsigned short* gBh = Wc + (size_t)(bn * 128 + wave * 32 + srow) * LDK + scol;
    const unsigned short* gAl = gAh + 512;
    const unsigned short* gBl = gBh + 512;
    unsigned short* lAh = &Ah[(wave * 32) * 32];
    unsigned short* lAl = &Al[(wave * 32) * 32];
    unsigned short* lBh = &Bh[(wave * 32) * 32];
    unsigned short* lBl = &Bl[(wave * 32) * 32];

    const unsigned short* pah = &Ah[(wr * 64 + t16) * 32 + quad * 8];
    const unsigned short* pal = &Al[(wr * 64 + t16) * 32 + quad * 8];
    const unsigned short* pbh = &Bh[(wc * 64 + t16) * 32 + quad * 8];
    const unsigned short* pbl = &Bl[(wc * 64 + t16) * 32 + quad * 8];

    floatx4 acc[4][4];
    #pragma unroll
    for (int i = 0; i < 4; ++i)
        #pragma unroll
        for (int j = 0; j < 4; ++j) acc[i][j] = (floatx4){0.f, 0.f, 0.f, 0.f};

    #pragma unroll 1
    for (int k0 = 0; k0 < DIM; k0 += 32) {
        __syncthreads();                       // prev tile fully consumed
        async16(gAh + k0,            lAh);
        async16(gAh + k0 + 16 * LDK, lAh + 16 * 32);
        async16(gAl + k0,            lAl);
        async16(gAl + k0 + 16 * LDK, lAl + 16 * 32);
        async16(gBh + k0,            lBh);
        async16(gBh + k0 + 16 * LDK, lBh + 16 * 32);
        async16(gBl + k0,            lBl);
        async16(gBl + k0 + 16 * LDK, lBl + 16 * 32);
        __syncthreads();                       // staged data visible

        short8 ah[4], bh[4], x[4];
        #pragma unroll
        for (int i = 0; i < 4; ++i) ah[i] = *(const short8*)(pah + i * 16 * 32);
        #pragma unroll
        for (int j = 0; j < 4; ++j) bh[j] = *(const short8*)(pbh + j * 16 * 32);
        #pragma unroll
        for (int i = 0; i < 4; ++i)
            #pragma unroll
            for (int j = 0; j < 4; ++j)
                acc[i][j] = __builtin_amdgcn_mfma_f32_16x16x32_bf16(
                    ah[i], bh[j], acc[i][j], 0, 0, 0);

        #pragma unroll
        for (int j = 0; j < 4; ++j) x[j] = *(const short8*)(pbl + j * 16 * 32);
        #pragma unroll
        for (int i = 0; i < 4; ++i)
            #pragma unroll
            for (int j = 0; j < 4; ++j)
                acc[i][j] = __builtin_amdgcn_mfma_f32_16x16x32_bf16(
                    ah[i], x[j], acc[i][j], 0, 0, 0);

        #pragma unroll
        for (int i = 0; i < 4; ++i) x[i] = *(const short8*)(pal + i * 16 * 32);
        #pragma unroll
        for (int i = 0; i < 4; ++i)
            #pragma unroll
            for (int j = 0; j < 4; ++j)
                acc[i][j] = __builtin_amdgcn_mfma_f32_16x16x32_bf16(
                    x[i], bh[j], acc[i][j], 0, 0, 0);
    }

    // Epilogue: val = w_sq - 2*dot. C/D layout: col=t16, row=quad*4+reg.
    {
        const int col0 = bn * 128 + wc * 64 + t16;
        float wq[4];
        #pragma unroll
        for (int j = 0; j < 4; ++j) wq[j] = w_sq[col0 + j * 16];
        const int row_base = bm * 128 + wr * 64 + quad * 4;
        #pragma unroll
        for (int i = 0; i < 4; ++i) {
            #pragma unroll
            for (int r = 0; r < 4; ++r) {
                unsigned long long best = ~0ull;
                #pragma unroll
                for (int j = 0; j < 4; ++j) {
                    float val = fmaf(-2.f, acc[i][j][r], wq[j]);
                    unsigned long long key = pack_key(val, col0 + j * 16);
                    best = (key < best) ? key : best;
                }
                #pragma unroll
                for (int m = 1; m <= 8; m <<= 1) {
                    unsigned long long o = __shfl_xor(best, m, 64);
                    best = (o < best) ? o : best;
                }
                if (t16 == 0)
                    atomicMin(&packed[row_base + i * 16 + r], best);
            }
        }
    }

    // ---- Per-bm completion: release-add; only bn==0 blocks poll + finalize ----
    __syncthreads();
    if (tid == 0)
        __hip_atomic_fetch_add(&done[bm], 1u, __ATOMIC_RELEASE, __HIP_MEMORY_SCOPE_AGENT);
    if (bn != 0) return;

    if (tid == 0) {
        while (__hip_atomic_load(&done[bm], __ATOMIC_RELAXED, __HIP_MEMORY_SCOPE_AGENT) < 32)
            __builtin_amdgcn_s_sleep(1);
    }
    __syncthreads();

    // ---------------- Phase C: finalize 128 rows of this bm group ----------------
    if (tid < 128) {
        int b = bm * 128 + tid;
        unsigned long long p = __hip_atomic_load(&packed[b], __ATOMIC_RELAXED,
                                                 __HIP_MEMORY_SCOPE_AGENT);
        unsigned idx = (unsigned)(p & 0xffffffffull);
        unsigned key = (unsigned)(p >> 32);
        unsigned u = (key & 0x80000000u) ? (key & 0x7fffffffu) : ~key;
        float val = __uint_as_float(u);
        float sq = fmaxf(x_sq[b] + val, 0.f);
        out[2 * b]     = (float)(idx >> 6);   // y = idx / 64
        out[2 * b + 1] = (float)(idx & 63);   // x = idx % 64
        out[2 * B_ROWS + b] = sqrtf(sq);
    }
}

extern "C" void kernel_launch(void* const* d_in, const int* in_sizes, int n_in,
                              void* d_out, int out_size, void* d_ws, size_t ws_size,
                              hipStream_t stream) {
    const float* X  = (const float*)d_in[0];   // (4096, 512)
    const float* Wt = (const float*)d_in[1];   // (64, 64, 512) -> (4096, 512)
    float* out = (float*)d_out;

    // ws layout: [0,32K) packed u64[4096]; [32K,48K) x_sq; [48K,64K) w_sq;
    // [64K,+256) ready[64]; [64K+256,+128) done[32]; [72K,+8M) Xc; [+8M,+16M) Wc.
    unsigned long long* packed = (unsigned long long*)d_ws;
    float* x_sq = (float*)((char*)d_ws + (32 << 10));
    float* w_sq = (float*)((char*)d_ws + (48 << 10));
    unsigned* ready = (unsigned*)((char*)d_ws + (64 << 10));
    unsigned* done  = (unsigned*)((char*)d_ws + (64 << 10) + 256);
    unsigned short* Xc = (unsigned short*)((char*)d_ws + (72 << 10));
    unsigned short* Wc = (unsigned short*)((char*)d_ws + (72 << 10) + ((size_t)B_ROWS * LDK * 2));

    hipMemsetAsync(ready, 0, 512, stream);   // zero ready[64] + done[32]
    som_fused<<<dim3(GRID), dim3(256), 0, stream>>>(
        X, Wt, Xc, Wc, x_sq, w_sq, packed, ready, done, out);
}

// Round 7
// 123.679 us; speedup vs baseline: 2.0071x; 1.6018x over previous
//
#include <hip/hip_runtime.h>

// Problem constants (fixed by setup_inputs): B=4096, D=512, H=W=64, N=4096.
#define B_ROWS 4096
#define N_COLS 4096
#define DIM    512
#define LDK    1024   // row stride (elements) of split bf16 arrays [hi(512) | lo(512)]

typedef __attribute__((ext_vector_type(8))) short short8;
typedef __attribute__((ext_vector_type(4))) float floatx4;

// bf16 round-to-nearest-even split helpers (bit-exact, no API dependence)
__device__ __forceinline__ unsigned short f2bf_rn(float f) {
    unsigned u = __float_as_uint(f);
    u += 0x7fffu + ((u >> 16) & 1u);
    return (unsigned short)(u >> 16);
}
__device__ __forceinline__ float bf2f(unsigned short h) {
    return __uint_as_float(((unsigned)h) << 16);
}

// Monotone float->uint map; (key<<32)|idx gives u64 atomicMin argmin with
// smallest-index tie-break (matches numpy argmin semantics).
__device__ __forceinline__ unsigned long long pack_key(float v, int idx) {
    unsigned u = __float_as_uint(v);
    u = (u & 0x80000000u) ? ~u : (u | 0x80000000u);
    return ((unsigned long long)u << 32) | (unsigned)idx;
}

// Async global->LDS, 16B per lane. LDS dest is wave-uniform base + lane*16.
__device__ __forceinline__ void async16(const unsigned short* g, unsigned short* l) {
    __builtin_amdgcn_global_load_lds(
        (__attribute__((address_space(1))) void*)g,
        (__attribute__((address_space(3))) void*)l, 16, 0, 0);
}

// One wave per row (4 rows/block): split fp32 row into bf16 hi/lo halves,
// compute exact fp32 ||row||^2, init packed argmin accumulators.
__global__ __launch_bounds__(256) void som_convert(
    const float* __restrict__ X, const float* __restrict__ Wt,
    unsigned short* __restrict__ Xc, unsigned short* __restrict__ Wc,
    float* __restrict__ x_sq, float* __restrict__ w_sq,
    unsigned long long* __restrict__ packed)
{
    int wave = threadIdx.x >> 6, lane = threadIdx.x & 63;
    int grow = blockIdx.x * 4 + wave;            // 0..8191
    bool isX = grow < B_ROWS;
    const float* src = isX ? (X + (size_t)grow * DIM)
                           : (Wt + (size_t)(grow - B_ROWS) * DIM);
    const float4* p4 = (const float4*)src;
    float4 a = p4[lane * 2], b = p4[lane * 2 + 1];
    float f[8] = {a.x, a.y, a.z, a.w, b.x, b.y, b.z, b.w};
    unsigned short hi[8], lo[8];
    float s = 0.f;
    #pragma unroll
    for (int t = 0; t < 8; ++t) {
        hi[t] = f2bf_rn(f[t]);
        lo[t] = f2bf_rn(f[t] - bf2f(hi[t]));
        s = fmaf(f[t], f[t], s);
    }
    unsigned short* dst = (isX ? Xc + (size_t)grow * LDK
                               : Wc + (size_t)(grow - B_ROWS) * LDK) + lane * 8;
    *(ushort4*)(dst)       = make_ushort4(hi[0], hi[1], hi[2], hi[3]);
    *(ushort4*)(dst + 4)   = make_ushort4(hi[4], hi[5], hi[6], hi[7]);
    *(ushort4*)(dst + 512) = make_ushort4(lo[0], lo[1], lo[2], lo[3]);
    *(ushort4*)(dst + 516) = make_ushort4(lo[4], lo[5], lo[6], lo[7]);
    #pragma unroll
    for (int off = 32; off >= 1; off >>= 1) s += __shfl_xor(s, off, 64);
    if (lane == 0) {
        if (isX) { x_sq[grow] = s; packed[grow] = ~0ull; }
        else     { w_sq[grow - B_ROWS] = s; }
    }
}

// Split-bf16 distance GEMM + fused per-row argmin. Merged 3-product K-loop.
//
// LDS BANK SWIZZLE (the R6->R7 change): fragment reads at
// (row*64B + quad*16B) put 8 lanes on the same 4-bank window (8-way
// conflict, ~2.9x — R3's 4.2e6 SQ_LDS_BANK_CONFLICT; kernel was LDS-bound).
// global_load_lds forces LDS dest = base + lane*16, so instead we swizzle
// WHICH global chunk each staging lane fetches: LDS slot s of row r holds
// global chunk (s ^ ((r>>1)&3)). Readers use s = quad ^ ((t16>>1)&3):
// within every 16-lane group the eight 4-bank windows get exactly 2 lanes
// each -> 2-way, which is free (m136). Coalescing unchanged (chunks are
// permuted within the same 64B line).
__global__ __launch_bounds__(256, 3) void som_dist_bf16(
    const unsigned short* __restrict__ Xc, const unsigned short* __restrict__ Wc,
    const float* __restrict__ w_sq, unsigned long long* __restrict__ packed)
{
    __shared__ unsigned short Ah[128 * 32];   // row-major, 32 elems (64 B)/row
    __shared__ unsigned short Al[128 * 32];
    __shared__ unsigned short Bh[128 * 32];
    __shared__ unsigned short Bl[128 * 32];
    const int tid  = threadIdx.x;
    const int wave = tid >> 6, lane = tid & 63;
    const int wr = wave >> 1, wc = wave & 1;       // 2x2 wave grid
    const int bm = blockIdx.y, bn = blockIdx.x;
    const int quad = lane >> 4, t16 = lane & 15;

    // Staging: wave stages rows [wave*32, wave*32+32) of all four tiles as
    // wave-contiguous 1024B chunks (16 rows x 64 B each), 8 async16/iter.
    const int srow = lane >> 2;                       // 0..15 row in chunk
    const int schunk = (lane & 3) ^ ((lane >> 3) & 3); // swizzled 16B chunk
    const int scol = schunk * 8;                      // element offset
    const unsigned short* gAh = Xc + (size_t)(bm * 128 + wave * 32 + srow) * LDK + scol;
    const unsigned short* gBh = Wc + (size_t)(bn * 128 + wave * 32 + srow) * LDK + scol;
    const unsigned short* gAl = gAh + 512;
    const unsigned short* gBl = gBh + 512;
    unsigned short* lAh = &Ah[(wave * 32) * 32];
    unsigned short* lAl = &Al[(wave * 32) * 32];
    unsigned short* lBh = &Bh[(wave * 32) * 32];
    unsigned short* lBl = &Bl[(wave * 32) * 32];

    // Fragment read pointers: slot = quad ^ ((t16>>1)&3) (un-swizzle)
    const int fslot = (quad ^ ((t16 >> 1) & 3)) * 8;
    const unsigned short* pah = &Ah[(wr * 64 + t16) * 32 + fslot];
    const unsigned short* pal = &Al[(wr * 64 + t16) * 32 + fslot];
    const unsigned short* pbh = &Bh[(wc * 64 + t16) * 32 + fslot];
    const unsigned short* pbl = &Bl[(wc * 64 + t16) * 32 + fslot];

    floatx4 acc[4][4];
    #pragma unroll
    for (int i = 0; i < 4; ++i)
        #pragma unroll
        for (int j = 0; j < 4; ++j) acc[i][j] = (floatx4){0.f, 0.f, 0.f, 0.f};

    #pragma unroll 1
    for (int k0 = 0; k0 < DIM; k0 += 32) {
        __syncthreads();                       // prev tile fully consumed
        async16(gAh + k0,            lAh);
        async16(gAh + k0 + 16 * LDK, lAh + 16 * 32);
        async16(gAl + k0,            lAl);
        async16(gAl + k0 + 16 * LDK, lAl + 16 * 32);
        async16(gBh + k0,            lBh);
        async16(gBh + k0 + 16 * LDK, lBh + 16 * 32);
        async16(gBl + k0,            lBl);
        async16(gBl + k0 + 16 * LDK, lBl + 16 * 32);
        __syncthreads();                       // staged data visible

        short8 ah[4], bh[4], x[4];
        #pragma unroll
        for (int i = 0; i < 4; ++i) ah[i] = *(const short8*)(pah + i * 16 * 32);
        #pragma unroll
        for (int j = 0; j < 4; ++j) bh[j] = *(const short8*)(pbh + j * 16 * 32);
        #pragma unroll
        for (int i = 0; i < 4; ++i)
            #pragma unroll
            for (int j = 0; j < 4; ++j)
                acc[i][j] = __builtin_amdgcn_mfma_f32_16x16x32_bf16(
                    ah[i], bh[j], acc[i][j], 0, 0, 0);

        #pragma unroll
        for (int j = 0; j < 4; ++j) x[j] = *(const short8*)(pbl + j * 16 * 32);
        #pragma unroll
        for (int i = 0; i < 4; ++i)
            #pragma unroll
            for (int j = 0; j < 4; ++j)
                acc[i][j] = __builtin_amdgcn_mfma_f32_16x16x32_bf16(
                    ah[i], x[j], acc[i][j], 0, 0, 0);

        #pragma unroll
        for (int i = 0; i < 4; ++i) x[i] = *(const short8*)(pal + i * 16 * 32);
        #pragma unroll
        for (int i = 0; i < 4; ++i)
            #pragma unroll
            for (int j = 0; j < 4; ++j)
                acc[i][j] = __builtin_amdgcn_mfma_f32_16x16x32_bf16(
                    x[i], bh[j], acc[i][j], 0, 0, 0);
    }

    // Epilogue: val = w_sq - 2*dot (x_sq is per-row constant, irrelevant to
    // argmin). C/D layout: col = t16, row = quad*4 + reg  [m89/m91].
    const int col0 = bn * 128 + wc * 64 + t16;
    float wq[4];
    #pragma unroll
    for (int j = 0; j < 4; ++j) wq[j] = w_sq[col0 + j * 16];
    const int row_base = bm * 128 + wr * 64 + quad * 4;
    #pragma unroll
    for (int i = 0; i < 4; ++i) {
        #pragma unroll
        for (int r = 0; r < 4; ++r) {
            unsigned long long best = ~0ull;
            #pragma unroll
            for (int j = 0; j < 4; ++j) {
                float val = fmaf(-2.f, acc[i][j][r], wq[j]);
                unsigned long long key = pack_key(val, col0 + j * 16);
                best = (key < best) ? key : best;
            }
            #pragma unroll
            for (int m = 1; m <= 8; m <<= 1) {     // reduce 16-lane col group
                unsigned long long o = __shfl_xor(best, m, 64);
                best = (o < best) ? o : best;
            }
            if (t16 == 0)
                atomicMin(&packed[row_base + i * 16 + r], best);
        }
    }
}

// Unpack argmin, qe = sqrt(max(||x||^2 + val, 0)).
// d_out: bmu_indices (4096 x 2) flat, then qe (4096), all float.
__global__ __launch_bounds__(256) void som_finalize(
    const unsigned long long* __restrict__ packed,
    const float* __restrict__ x_sq, float* __restrict__ out)
{
    int b = blockIdx.x * 256 + threadIdx.x;  // 0..4095
    unsigned long long p = packed[b];
    unsigned idx = (unsigned)(p & 0xffffffffull);
    unsigned key = (unsigned)(p >> 32);
    unsigned u = (key & 0x80000000u) ? (key & 0x7fffffffu) : ~key;
    float val = __uint_as_float(u);
    float sq = fmaxf(x_sq[b] + val, 0.f);
    out[2 * b]     = (float)(idx >> 6);   // y = idx / 64
    out[2 * b + 1] = (float)(idx & 63);   // x = idx % 64
    out[2 * B_ROWS + b] = sqrtf(sq);
}

extern "C" void kernel_launch(void* const* d_in, const int* in_sizes, int n_in,
                              void* d_out, int out_size, void* d_ws, size_t ws_size,
                              hipStream_t stream) {
    const float* X  = (const float*)d_in[0];   // (4096, 512)
    const float* Wt = (const float*)d_in[1];   // (64, 64, 512) -> (4096, 512)
    float* out = (float*)d_out;

    // ws layout: [0,32K) packed u64[4096]; [32K,48K) x_sq; [48K,64K) w_sq;
    // [64K, 64K+8M) Xc bf16 split; [64K+8M, 64K+16M) Wc bf16 split.
    unsigned long long* packed = (unsigned long long*)d_ws;
    float* x_sq = (float*)((char*)d_ws + (32 << 10));
    float* w_sq = (float*)((char*)d_ws + (48 << 10));
    unsigned short* Xc = (unsigned short*)((char*)d_ws + (64 << 10));
    unsigned short* Wc = (unsigned short*)((char*)d_ws + (64 << 10) + ((size_t)B_ROWS * LDK * 2));

    som_convert<<<dim3((B_ROWS + N_COLS) / 4), dim3(256), 0, stream>>>(
        X, Wt, Xc, Wc, x_sq, w_sq, packed);
    som_dist_bf16<<<dim3(N_COLS / 128, B_ROWS / 128), dim3(256), 0, stream>>>(
        Xc, Wc, w_sq, packed);
    som_finalize<<<dim3(B_ROWS / 256), dim3(256), 0, stream>>>(packed, x_sq, out);
}